// Round 14
// baseline (185.156 us; speedup 1.0000x reference)
//
#include <hip/hip_runtime.h>

#define N_NODES  50000
#define N_EDGESC 1600000
#define N_GRAPHS 64
#define NBUCK    196      // ceil(50000/256) buckets of 256 dst nodes
#define CHUNK    2048     // edges per hist/scatter block
#define NBLK     782      // ceil(E/CHUNK)

static __device__ __forceinline__ unsigned short f2bf(float f) {
  unsigned u = __float_as_uint(f);
  u += 0x7FFF + ((u >> 16) & 1);          // RNE
  return (unsigned short)(u >> 16);
}
static __device__ __forceinline__ float bfLo(unsigned u) {
  return __uint_as_float(u << 16);
}
static __device__ __forceinline__ float bfHi(unsigned u) {
  return __uint_as_float(u & 0xFFFF0000u);
}

static __device__ __forceinline__ int lowerb(const int* a, int n, int v) {
  int lo = 0, hi = n;
  while (lo < hi) { int m = (lo + hi) >> 1; if (a[m] < v) lo = m + 1; else hi = m; }
  return lo;
}

// Pass 1: per-block bucket histogram (LDS only) -> bcnt[bucket][blk].
// Block 0 also zeros gsum.
__global__ __launch_bounds__(256) void k_hist(const int* __restrict__ dst,
                                              int* __restrict__ bcnt,
                                              float* __restrict__ gsum, int E) {
  __shared__ int hist[NBUCK];
  int t = threadIdx.x, blk = blockIdx.x;
  if (t < NBUCK) hist[t] = 0;
  if (blk == 0) {
    for (int i = t; i < N_GRAPHS * 64; i += 256) gsum[i] = 0.f;
  }
  __syncthreads();
  int e0 = blk * CHUNK;
#pragma unroll
  for (int i = 0; i < CHUNK; i += 256) {
    int e = e0 + i + t;
    if (e < E) atomicAdd(&hist[dst[e] >> 8], 1);
  }
  __syncthreads();
  if (t < NBUCK) bcnt[(size_t)t * NBLK + blk] = hist[t];
}

// Pass 2: per-bucket exclusive scan across blocks (in place) + bucket totals.
__global__ __launch_bounds__(256) void k_cscan(int* __restrict__ bcnt,
                                               int* __restrict__ btot) {
  __shared__ int sm[256];
  int b = blockIdx.x, t = threadIdx.x;
  int* p = bcnt + (size_t)b * NBLK;
  int carry = 0;
  for (int tile = 0; tile < (NBLK + 255) / 256; ++tile) {
    int idx = tile * 256 + t;
    int v = (idx < NBLK) ? p[idx] : 0;
    sm[t] = v;
    __syncthreads();
    for (int o = 1; o < 256; o <<= 1) {
      int add = (t >= o) ? sm[t - o] : 0;
      __syncthreads();
      sm[t] += add;
      __syncthreads();
    }
    int incl = sm[t];
    int total = sm[255];
    if (idx < NBLK) p[idx] = incl - v + carry;
    carry += total;
    __syncthreads();
  }
  if (t == 0) btot[b] = carry;
}

// Pass 3: scatter edges to final bucket-contiguous positions.
__global__ __launch_bounds__(256) void k_scatter(const int* __restrict__ src,
                                                 const int* __restrict__ dst,
                                                 const int* __restrict__ bcnt,
                                                 const int* __restrict__ btot,
                                                 unsigned* __restrict__ bbuf, int E) {
  __shared__ int base[NBUCK], cur[NBUCK], sm[256];
  int t = threadIdx.x, blk = blockIdx.x;
  int v = (t < NBUCK) ? btot[t] : 0;
  sm[t] = v;
  __syncthreads();
  for (int o = 1; o < 256; o <<= 1) {
    int add = (t >= o) ? sm[t - o] : 0;
    __syncthreads();
    sm[t] += add;
    __syncthreads();
  }
  if (t < NBUCK) {
    base[t] = (sm[t] - v) + bcnt[(size_t)t * NBLK + blk];
    cur[t] = 0;
  }
  __syncthreads();
  int e0 = blk * CHUNK;
#pragma unroll
  for (int i = 0; i < CHUNK; i += 256) {
    int e = e0 + i + t;
    if (e < E) {
      int d = dst[e], b = d >> 8;
      int pos = base[b] + atomicAdd(&cur[b], 1);
      bbuf[pos] = ((unsigned)(d & 255) << 24) | (unsigned)src[e];
    }
  }
}

// Pass 4: per-bucket counting sort -> csr + row_off + dinv. 512 threads.
__global__ __launch_bounds__(512) void k_bsort(const unsigned* __restrict__ bbuf,
                                               const int* __restrict__ btot,
                                               int* __restrict__ csr,
                                               int* __restrict__ row_off,
                                               float* __restrict__ dinv) {
  __shared__ int hist[256], off[256], cur[256], sm[256];
  int b = blockIdx.x, t = threadIdx.x;
  if (t < 256) {
    int v = (t < NBUCK) ? btot[t] : 0;
    sm[t] = v;
    hist[t] = 0; cur[t] = 0;
  }
  __syncthreads();
  for (int o = 1; o < 256; o <<= 1) {
    int add = 0;
    if (t < 256 && t >= o) add = sm[t - o];
    __syncthreads();
    if (t < 256) sm[t] += add;
    __syncthreads();
  }
  int gb = (b > 0) ? sm[b - 1] : 0;
  int cnt = btot[b];
  const unsigned* bp = bbuf + gb;
  for (int i = t; i < cnt; i += 512) atomicAdd(&hist[bp[i] >> 24], 1);
  __syncthreads();
  if (t < 256) off[t] = hist[t];
  __syncthreads();
  for (int o = 1; o < 256; o <<= 1) {
    int add = 0;
    if (t < 256 && t >= o) add = off[t - o];
    __syncthreads();
    if (t < 256) off[t] += add;
    __syncthreads();
  }
  if (t < 256) {
    int excl = off[t] - hist[t];
    off[t] = excl;
    int idx = (b << 8) + t;
    if (idx <= N_NODES) row_off[idx] = gb + excl;
    if (idx < N_NODES)  dinv[idx] = rsqrtf((float)(hist[t] + 1));  // +1 self-loop
  }
  __syncthreads();
  for (int i = t; i < cnt; i += 512) {
    unsigned v = bp[i];
    int ld = v >> 24;
    int pos = atomicAdd(&cur[ld], 1);
    csr[gb + off[ld] + pos] = (int)(v & 0xFFFFFFu);
  }
}

// out_bf16[i][c] = bf16( (x[i,:] @ W[:,c]) * dinv[i] )
template <int K>
__global__ __launch_bounds__(256) void k_gemm(const float* __restrict__ x,
                                              const float* __restrict__ W,
                                              const float* __restrict__ dinv,
                                              unsigned short* __restrict__ out, int N) {
  constexpr int KS = 64;            // K-step
  constexpr int KP = KS + 4;        // padded xs row stride
  __shared__ float xs[64 * KP];     // 17.4 KB
  __shared__ float Wl[KS * 64];     // 16 KB
  const int t = threadIdx.x;
  const int lane = t & 63;
  const int w = t >> 6;
  const int n0 = blockIdx.x * 64;

  float acc[16];
#pragma unroll
  for (int j = 0; j < 16; ++j) acc[j] = 0.f;

  for (int h = 0; h < K / KS; ++h) {
#pragma unroll
    for (int i = 0; i < KS * 16 / 256; ++i) {
      int li = i * 256 + t;
      float4 v = reinterpret_cast<const float4*>(W + h * KS * 64)[li];
      *reinterpret_cast<float4*>(Wl + li * 4) = v;
    }
#pragma unroll
    for (int i = 0; i < 64 * (KS / 4) / 256; ++i) {
      int li = i * 256 + t;
      int row = li / (KS / 4), c4 = li % (KS / 4);
      int node = n0 + row;
      float4 v = make_float4(0.f, 0.f, 0.f, 0.f);
      if (node < N) v = reinterpret_cast<const float4*>(x + (size_t)node * K + h * KS)[c4];
      *reinterpret_cast<float4*>(xs + row * KP + c4 * 4) = v;
    }
    __syncthreads();

    const float* xr = xs + lane * KP;
    const float* wq = Wl + w * 16;
#pragma unroll 4
    for (int kp = 0; kp < KS / 4; ++kp) {
      float4 xv = *reinterpret_cast<const float4*>(xr + kp * 4);
#pragma unroll
      for (int q = 0; q < 4; ++q) {
        int k = kp * 4 + q;
        float xq = (q == 0) ? xv.x : (q == 1) ? xv.y : (q == 2) ? xv.z : xv.w;
        const float* wk = wq + k * 64;                 // wave-uniform address
        float4 w0 = *reinterpret_cast<const float4*>(wk);
        float4 w1 = *reinterpret_cast<const float4*>(wk + 4);
        float4 w2 = *reinterpret_cast<const float4*>(wk + 8);
        float4 w3 = *reinterpret_cast<const float4*>(wk + 12);
        acc[ 0] = fmaf(xq, w0.x, acc[ 0]);
        acc[ 1] = fmaf(xq, w0.y, acc[ 1]);
        acc[ 2] = fmaf(xq, w0.z, acc[ 2]);
        acc[ 3] = fmaf(xq, w0.w, acc[ 3]);
        acc[ 4] = fmaf(xq, w1.x, acc[ 4]);
        acc[ 5] = fmaf(xq, w1.y, acc[ 5]);
        acc[ 6] = fmaf(xq, w1.z, acc[ 6]);
        acc[ 7] = fmaf(xq, w1.w, acc[ 7]);
        acc[ 8] = fmaf(xq, w2.x, acc[ 8]);
        acc[ 9] = fmaf(xq, w2.y, acc[ 9]);
        acc[10] = fmaf(xq, w2.z, acc[10]);
        acc[11] = fmaf(xq, w2.w, acc[11]);
        acc[12] = fmaf(xq, w3.x, acc[12]);
        acc[13] = fmaf(xq, w3.y, acc[13]);
        acc[14] = fmaf(xq, w3.z, acc[14]);
        acc[15] = fmaf(xq, w3.w, acc[15]);
      }
    }
    __syncthreads();   // before next half restages
  }

  int node = n0 + lane;
  if (node < N) {
    float dv = dinv[node];
    unsigned pk[8];
#pragma unroll
    for (int j = 0; j < 8; ++j) {
      unsigned lo = f2bf(acc[2 * j] * dv);
      unsigned hi = f2bf(acc[2 * j + 1] * dv);
      pk[j] = lo | (hi << 16);
    }
    unsigned* op = reinterpret_cast<unsigned*>(out + (size_t)node * 64 + w * 16);
    *reinterpret_cast<uint4*>(op)     = make_uint4(pk[0], pk[1], pk[2], pk[3]);
    *reinterpret_cast<uint4*>(op + 4) = make_uint4(pk[4], pk[5], pk[6], pk[7]);
  }
}

// out[i][c] = relu( dinv[i]*(hs[i][c] + sum_{s} hs[s][c]) + bias[c] ), hs bf16.
// Slot/pos gather with SOFTWARE-PIPELINED csr index loads: batch n+1's 4
// indices are issued before batch n's accumulate, hiding index latency
// under the current batch's feature loads.
__global__ __launch_bounds__(256) void k_gather(const unsigned short* __restrict__ hs,
                                                const int* __restrict__ row_off,
                                                const int* __restrict__ csr,
                                                const float* __restrict__ dinv,
                                                const float* __restrict__ bias,
                                                float* __restrict__ out, int N) {
  const int lane = threadIdx.x & 63;
  const int slot = lane >> 3;        // edge slot (8 edges per instruction)
  const int pos  = lane & 7;         // 16B chunk within 128B row
  int wid = blockIdx.x * 4 + (threadIdx.x >> 6);
  int stride = gridDim.x * 4;
  const uint4* hsq = reinterpret_cast<const uint4*>(hs);
  float4 bA = reinterpret_cast<const float4*>(bias)[pos * 2];
  float4 bB = reinterpret_cast<const float4*>(bias)[pos * 2 + 1];
  for (int i = wid; i < N; i += stride) {
    float a[8];
    {  // self-loop: count once (slot 0 only)
      uint4 sv = hsq[(((unsigned)i) << 3) + pos];
      if (slot == 0) {
        a[0] = bfLo(sv.x); a[1] = bfHi(sv.x); a[2] = bfLo(sv.y); a[3] = bfHi(sv.y);
        a[4] = bfLo(sv.z); a[5] = bfHi(sv.z); a[6] = bfLo(sv.w); a[7] = bfHi(sv.w);
      } else {
#pragma unroll
        for (int k = 0; k < 8; ++k) a[k] = 0.f;
      }
    }
    const int s0 = row_off[i], s1 = row_off[i + 1];
    int j = s0;
    int idx[4];
    if (j + 32 <= s1) {
#pragma unroll
      for (int q = 0; q < 4; ++q) idx[q] = csr[j + 8 * q + slot];
    }
    for (; j + 32 <= s1; ) {
      uint4 v[4];
#pragma unroll
      for (int q = 0; q < 4; ++q)
        v[q] = hsq[(((unsigned)idx[q]) << 3) + pos];   // 4x1KB in flight
      int jn = j + 32;
      if (jn + 32 <= s1) {                              // prefetch next indices
#pragma unroll
        for (int q = 0; q < 4; ++q) idx[q] = csr[jn + 8 * q + slot];
      }
#pragma unroll
      for (int q = 0; q < 4; ++q) {
        a[0] += bfLo(v[q].x); a[1] += bfHi(v[q].x);
        a[2] += bfLo(v[q].y); a[3] += bfHi(v[q].y);
        a[4] += bfLo(v[q].z); a[5] += bfHi(v[q].z);
        a[6] += bfLo(v[q].w); a[7] += bfHi(v[q].w);
      }
      j = jn;
    }
    if (j < s1) {                                      // clamped masked tail
      int idxt[4];
      bool ok[4];
#pragma unroll
      for (int q = 0; q < 4; ++q) {
        int e = j + 8 * q + slot;
        ok[q] = e < s1;
        idxt[q] = csr[min(e, s1 - 1)];
      }
      uint4 v[4];
#pragma unroll
      for (int q = 0; q < 4; ++q)
        v[q] = hsq[(((unsigned)idxt[q]) << 3) + pos];
#pragma unroll
      for (int q = 0; q < 4; ++q) {
        if (ok[q]) {
          a[0] += bfLo(v[q].x); a[1] += bfHi(v[q].x);
          a[2] += bfLo(v[q].y); a[3] += bfHi(v[q].y);
          a[4] += bfLo(v[q].z); a[5] += bfHi(v[q].z);
          a[6] += bfLo(v[q].w); a[7] += bfHi(v[q].w);
        }
      }
    }
    // fold across 8 slots
#pragma unroll
    for (int k = 0; k < 8; ++k) {
      a[k] += __shfl_xor(a[k], 8);
      a[k] += __shfl_xor(a[k], 16);
      a[k] += __shfl_xor(a[k], 32);
    }
    if (slot == 0) {
      float dv = dinv[i];
      float4 rA, rB;
      rA.x = fmaxf(fmaf(a[0], dv, bA.x), 0.f);
      rA.y = fmaxf(fmaf(a[1], dv, bA.y), 0.f);
      rA.z = fmaxf(fmaf(a[2], dv, bA.z), 0.f);
      rA.w = fmaxf(fmaf(a[3], dv, bA.w), 0.f);
      rB.x = fmaxf(fmaf(a[4], dv, bB.x), 0.f);
      rB.y = fmaxf(fmaf(a[5], dv, bB.y), 0.f);
      rB.z = fmaxf(fmaf(a[6], dv, bB.z), 0.f);
      rB.w = fmaxf(fmaf(a[7], dv, bB.w), 0.f);
      float4* op = reinterpret_cast<float4*>(out + (((size_t)i) << 6) + pos * 8);
      op[0] = rA;
      op[1] = rB;
    }
  }
}

// Stage-1 pool: wave handles 16 rows; batch sorted -> graph id wave-uniform;
// one fp32 atomicAdd per segment per channel.
__global__ __launch_bounds__(256) void k_pool1(const float* __restrict__ h,
                                               const int* __restrict__ batch,
                                               float* __restrict__ gsum, int N) {
  int c = threadIdx.x & 63;
  int w = threadIdx.x >> 6;
  int r0 = blockIdx.x * 64 + w * 16;
  if (r0 >= N) return;
  int r1 = min(r0 + 16, N);
  int gprev = batch[r0];
  float acc = 0.f;
  for (int r = r0; r < r1; ++r) {
    int g = batch[r];                        // wave-uniform
    if (g != gprev) { atomicAdd(&gsum[gprev * 64 + c], acc); acc = 0.f; gprev = g; }
    acc += h[(size_t)r * 64 + c];            // coalesced 256B row
  }
  atomicAdd(&gsum[gprev * 64 + c], acc);
}

// Final projection; per-block binary searches for segment sizes.
__global__ void k_final(const float* __restrict__ gsum, const int* __restrict__ batch,
                        const float* __restrict__ Wp, const float* __restrict__ bp,
                        float* __restrict__ out, int N) {
  __shared__ int lb[5];
  int t = threadIdx.x;
  int g0 = blockIdx.x * 4;
  if (t < 5) lb[t] = lowerb(batch, N, g0 + t);
  __syncthreads();
  int idx = blockIdx.x * 256 + t;
  int g = idx >> 6, o = idx & 63, gl = g & 3;
  float cinv = 1.0f / fmaxf((float)(lb[gl + 1] - lb[gl]), 1.0f);
  float acc = 0.f;
#pragma unroll
  for (int k = 0; k < 64; ++k) acc += gsum[g * 64 + k] * Wp[k * 64 + o];
  out[idx] = fmaf(acc, cinv, bp[o]);
}

extern "C" void kernel_launch(void* const* d_in, const int* in_sizes, int n_in,
                              void* d_out, int out_size, void* d_ws, size_t ws_size,
                              hipStream_t stream) {
  const float* x    = (const float*)d_in[0];
  const float* W1   = (const float*)d_in[1];
  const float* b1   = (const float*)d_in[2];
  const float* W2   = (const float*)d_in[3];
  const float* b2   = (const float*)d_in[4];
  const float* Wp   = (const float*)d_in[5];
  const float* bp   = (const float*)d_in[6];
  const int*   ei   = (const int*)d_in[7];
  const int*   batch= (const int*)d_in[8];
  float* out = (float*)d_out;

  const int N = N_NODES, E = N_EDGESC;
  const int* src  = ei;        // edge_index[0]
  const int* dstp = ei + E;    // edge_index[1]

  char* wsb = (char*)d_ws;
  size_t o = 0;
  auto alloc = [&](size_t bytes) -> void* {
    void* p = wsb + o;
    o = (o + bytes + 255) & ~(size_t)255;
    return p;
  };
  int*      bcnt   = (int*)alloc((size_t)NBUCK * NBLK * 4);
  int*      btot   = (int*)alloc(NBUCK * 4);
  unsigned* bbuf   = (unsigned*)alloc((size_t)E * 4);
  int*      row_off= (int*)alloc((size_t)(N + 1) * 4);
  int*      csr    = (int*)alloc((size_t)E * 4);
  float*    dinv   = (float*)alloc((size_t)N * 4);
  unsigned short* bufBF = (unsigned short*)alloc((size_t)N * 64 * 2);
  float*    bufF   = (float*)alloc((size_t)N * 64 * 4);
  float*    gsum   = (float*)alloc(64 * 64 * 4);

  int gN64 = (N + 63) / 64;           // 782

  k_hist<<<NBLK, 256, 0, stream>>>(dstp, bcnt, gsum, E);
  k_cscan<<<NBUCK, 256, 0, stream>>>(bcnt, btot);
  k_scatter<<<NBLK, 256, 0, stream>>>(src, dstp, bcnt, btot, bbuf, E);
  k_bsort<<<NBUCK, 512, 0, stream>>>(bbuf, btot, csr, row_off, dinv);

  k_gemm<128><<<gN64, 256, 0, stream>>>(x, W1, dinv, bufBF, N);
  k_gather<<<2048, 256, 0, stream>>>(bufBF, row_off, csr, dinv, b1, bufF, N);
  k_gemm<64><<<gN64, 256, 0, stream>>>(bufF, W2, dinv, bufBF, N);
  k_gather<<<2048, 256, 0, stream>>>(bufBF, row_off, csr, dinv, b2, bufF, N);

  k_pool1<<<gN64, 256, 0, stream>>>(bufF, batch, gsum, N);
  k_final<<<16, 256, 0, stream>>>(gsum, batch, Wp, bp, out, N);
}

// Round 15
// 161.255 us; speedup vs baseline: 1.1482x; 1.1482x over previous
//
#include <hip/hip_runtime.h>

#define N_NODES  50000
#define N_EDGESC 1600000
#define N_GRAPHS 64
#define NBUCK    196      // ceil(50000/256) buckets of 256 dst nodes
#define CHUNK    2048     // edges per hist/scatter block
#define NBLK     782      // ceil(E/CHUNK)

static __device__ __forceinline__ unsigned short f2bf(float f) {
  unsigned u = __float_as_uint(f);
  u += 0x7FFF + ((u >> 16) & 1);          // RNE
  return (unsigned short)(u >> 16);
}
static __device__ __forceinline__ float bfLo(unsigned u) {
  return __uint_as_float(u << 16);
}
static __device__ __forceinline__ float bfHi(unsigned u) {
  return __uint_as_float(u & 0xFFFF0000u);
}

static __device__ __forceinline__ int lowerb(const int* a, int n, int v) {
  int lo = 0, hi = n;
  while (lo < hi) { int m = (lo + hi) >> 1; if (a[m] < v) lo = m + 1; else hi = m; }
  return lo;
}

// Pass 1: per-block bucket histogram (LDS only) -> bcnt[bucket][blk].
// Block 0 also zeros gsum.
__global__ __launch_bounds__(256) void k_hist(const int* __restrict__ dst,
                                              int* __restrict__ bcnt,
                                              float* __restrict__ gsum, int E) {
  __shared__ int hist[NBUCK];
  int t = threadIdx.x, blk = blockIdx.x;
  if (t < NBUCK) hist[t] = 0;
  if (blk == 0) {
    for (int i = t; i < N_GRAPHS * 64; i += 256) gsum[i] = 0.f;
  }
  __syncthreads();
  int e0 = blk * CHUNK;
#pragma unroll
  for (int i = 0; i < CHUNK; i += 256) {
    int e = e0 + i + t;
    if (e < E) atomicAdd(&hist[dst[e] >> 8], 1);
  }
  __syncthreads();
  if (t < NBUCK) bcnt[(size_t)t * NBLK + blk] = hist[t];
}

// Pass 2: per-bucket exclusive scan across blocks (in place) + bucket totals.
__global__ __launch_bounds__(256) void k_cscan(int* __restrict__ bcnt,
                                               int* __restrict__ btot) {
  __shared__ int sm[256];
  int b = blockIdx.x, t = threadIdx.x;
  int* p = bcnt + (size_t)b * NBLK;
  int carry = 0;
  for (int tile = 0; tile < (NBLK + 255) / 256; ++tile) {
    int idx = tile * 256 + t;
    int v = (idx < NBLK) ? p[idx] : 0;
    sm[t] = v;
    __syncthreads();
    for (int o = 1; o < 256; o <<= 1) {
      int add = (t >= o) ? sm[t - o] : 0;
      __syncthreads();
      sm[t] += add;
      __syncthreads();
    }
    int incl = sm[t];
    int total = sm[255];
    if (idx < NBLK) p[idx] = incl - v + carry;
    carry += total;
    __syncthreads();
  }
  if (t == 0) btot[b] = carry;
}

// Pass 3: scatter edges to final bucket-contiguous positions.
__global__ __launch_bounds__(256) void k_scatter(const int* __restrict__ src,
                                                 const int* __restrict__ dst,
                                                 const int* __restrict__ bcnt,
                                                 const int* __restrict__ btot,
                                                 unsigned* __restrict__ bbuf, int E) {
  __shared__ int base[NBUCK], cur[NBUCK], sm[256];
  int t = threadIdx.x, blk = blockIdx.x;
  int v = (t < NBUCK) ? btot[t] : 0;
  sm[t] = v;
  __syncthreads();
  for (int o = 1; o < 256; o <<= 1) {
    int add = (t >= o) ? sm[t - o] : 0;
    __syncthreads();
    sm[t] += add;
    __syncthreads();
  }
  if (t < NBUCK) {
    base[t] = (sm[t] - v) + bcnt[(size_t)t * NBLK + blk];
    cur[t] = 0;
  }
  __syncthreads();
  int e0 = blk * CHUNK;
#pragma unroll
  for (int i = 0; i < CHUNK; i += 256) {
    int e = e0 + i + t;
    if (e < E) {
      int d = dst[e], b = d >> 8;
      int pos = base[b] + atomicAdd(&cur[b], 1);
      bbuf[pos] = ((unsigned)(d & 255) << 24) | (unsigned)src[e];
    }
  }
}

// Pass 4: per-bucket counting sort -> csr + row_off + dinv. 512 threads.
__global__ __launch_bounds__(512) void k_bsort(const unsigned* __restrict__ bbuf,
                                               const int* __restrict__ btot,
                                               int* __restrict__ csr,
                                               int* __restrict__ row_off,
                                               float* __restrict__ dinv) {
  __shared__ int hist[256], off[256], cur[256], sm[256];
  int b = blockIdx.x, t = threadIdx.x;
  if (t < 256) {
    int v = (t < NBUCK) ? btot[t] : 0;
    sm[t] = v;
    hist[t] = 0; cur[t] = 0;
  }
  __syncthreads();
  for (int o = 1; o < 256; o <<= 1) {
    int add = 0;
    if (t < 256 && t >= o) add = sm[t - o];
    __syncthreads();
    if (t < 256) sm[t] += add;
    __syncthreads();
  }
  int gb = (b > 0) ? sm[b - 1] : 0;
  int cnt = btot[b];
  const unsigned* bp = bbuf + gb;
  for (int i = t; i < cnt; i += 512) atomicAdd(&hist[bp[i] >> 24], 1);
  __syncthreads();
  if (t < 256) off[t] = hist[t];
  __syncthreads();
  for (int o = 1; o < 256; o <<= 1) {
    int add = 0;
    if (t < 256 && t >= o) add = off[t - o];
    __syncthreads();
    if (t < 256) off[t] += add;
    __syncthreads();
  }
  if (t < 256) {
    int excl = off[t] - hist[t];
    off[t] = excl;
    int idx = (b << 8) + t;
    if (idx <= N_NODES) row_off[idx] = gb + excl;
    if (idx < N_NODES)  dinv[idx] = rsqrtf((float)(hist[t] + 1));  // +1 self-loop
  }
  __syncthreads();
  for (int i = t; i < cnt; i += 512) {
    unsigned v = bp[i];
    int ld = v >> 24;
    int pos = atomicAdd(&cur[ld], 1);
    csr[gb + off[ld] + pos] = (int)(v & 0xFFFFFFu);
  }
}

// out_bf16[i][c] = bf16( (x[i,:] @ W[:,c]) * dinv[i] )
template <int K>
__global__ __launch_bounds__(256) void k_gemm(const float* __restrict__ x,
                                              const float* __restrict__ W,
                                              const float* __restrict__ dinv,
                                              unsigned short* __restrict__ out, int N) {
  constexpr int KS = 64;            // K-step
  constexpr int KP = KS + 4;        // padded xs row stride
  __shared__ float xs[64 * KP];     // 17.4 KB
  __shared__ float Wl[KS * 64];     // 16 KB
  const int t = threadIdx.x;
  const int lane = t & 63;
  const int w = t >> 6;
  const int n0 = blockIdx.x * 64;

  float acc[16];
#pragma unroll
  for (int j = 0; j < 16; ++j) acc[j] = 0.f;

  for (int h = 0; h < K / KS; ++h) {
#pragma unroll
    for (int i = 0; i < KS * 16 / 256; ++i) {
      int li = i * 256 + t;
      float4 v = reinterpret_cast<const float4*>(W + h * KS * 64)[li];
      *reinterpret_cast<float4*>(Wl + li * 4) = v;
    }
#pragma unroll
    for (int i = 0; i < 64 * (KS / 4) / 256; ++i) {
      int li = i * 256 + t;
      int row = li / (KS / 4), c4 = li % (KS / 4);
      int node = n0 + row;
      float4 v = make_float4(0.f, 0.f, 0.f, 0.f);
      if (node < N) v = reinterpret_cast<const float4*>(x + (size_t)node * K + h * KS)[c4];
      *reinterpret_cast<float4*>(xs + row * KP + c4 * 4) = v;
    }
    __syncthreads();

    const float* xr = xs + lane * KP;
    const float* wq = Wl + w * 16;
#pragma unroll 4
    for (int kp = 0; kp < KS / 4; ++kp) {
      float4 xv = *reinterpret_cast<const float4*>(xr + kp * 4);
#pragma unroll
      for (int q = 0; q < 4; ++q) {
        int k = kp * 4 + q;
        float xq = (q == 0) ? xv.x : (q == 1) ? xv.y : (q == 2) ? xv.z : xv.w;
        const float* wk = wq + k * 64;                 // wave-uniform address
        float4 w0 = *reinterpret_cast<const float4*>(wk);
        float4 w1 = *reinterpret_cast<const float4*>(wk + 4);
        float4 w2 = *reinterpret_cast<const float4*>(wk + 8);
        float4 w3 = *reinterpret_cast<const float4*>(wk + 12);
        acc[ 0] = fmaf(xq, w0.x, acc[ 0]);
        acc[ 1] = fmaf(xq, w0.y, acc[ 1]);
        acc[ 2] = fmaf(xq, w0.z, acc[ 2]);
        acc[ 3] = fmaf(xq, w0.w, acc[ 3]);
        acc[ 4] = fmaf(xq, w1.x, acc[ 4]);
        acc[ 5] = fmaf(xq, w1.y, acc[ 5]);
        acc[ 6] = fmaf(xq, w1.z, acc[ 6]);
        acc[ 7] = fmaf(xq, w1.w, acc[ 7]);
        acc[ 8] = fmaf(xq, w2.x, acc[ 8]);
        acc[ 9] = fmaf(xq, w2.y, acc[ 9]);
        acc[10] = fmaf(xq, w2.z, acc[10]);
        acc[11] = fmaf(xq, w2.w, acc[11]);
        acc[12] = fmaf(xq, w3.x, acc[12]);
        acc[13] = fmaf(xq, w3.y, acc[13]);
        acc[14] = fmaf(xq, w3.z, acc[14]);
        acc[15] = fmaf(xq, w3.w, acc[15]);
      }
    }
    __syncthreads();   // before next half restages
  }

  int node = n0 + lane;
  if (node < N) {
    float dv = dinv[node];
    unsigned pk[8];
#pragma unroll
    for (int j = 0; j < 8; ++j) {
      unsigned lo = f2bf(acc[2 * j] * dv);
      unsigned hi = f2bf(acc[2 * j + 1] * dv);
      pk[j] = lo | (hi << 16);
    }
    unsigned* op = reinterpret_cast<unsigned*>(out + (size_t)node * 64 + w * 16);
    *reinterpret_cast<uint4*>(op)     = make_uint4(pk[0], pk[1], pk[2], pk[3]);
    *reinterpret_cast<uint4*>(op + 4) = make_uint4(pk[4], pk[5], pk[6], pk[7]);
  }
}

// out[i][c] = relu( dinv[i]*(hs[i][c] + sum_{s} hs[s][c]) + bias[c] ), hs bf16.
// One-node-per-slot gather (fold-free): lane = (slot=lane>>3, pos=lane&7);
// wave owns 8 consecutive nodes, slot s aggregates node n0+s entirely.
// No shfls, no divergent epilogue; all 64 lanes write 1KB coalesced.
__global__ __launch_bounds__(256) void k_gather(const unsigned short* __restrict__ hs,
                                                const int* __restrict__ row_off,
                                                const int* __restrict__ csr,
                                                const float* __restrict__ dinv,
                                                const float* __restrict__ bias,
                                                float* __restrict__ out, int N) {
  const int lane = threadIdx.x & 63;
  const int slot = lane >> 3;        // which of the wave's 8 nodes
  const int pos  = lane & 7;         // 16B chunk within 128B row
  int n0 = (blockIdx.x * 4 + (threadIdx.x >> 6)) * 8;
  if (n0 >= N) return;               // N % 8 == 0 -> full groups only
  const int node = n0 + slot;
  const uint4* hsq = reinterpret_cast<const uint4*>(hs);
  float4 bA = reinterpret_cast<const float4*>(bias)[pos * 2];
  float4 bB = reinterpret_cast<const float4*>(bias)[pos * 2 + 1];

  const int s0 = row_off[node];
  const int deg = row_off[node + 1] - s0;

  float a[8];
  {  // self-loop term (every slot initializes with its own node's row)
    uint4 sv = hsq[(((unsigned)node) << 3) + pos];
    a[0] = bfLo(sv.x); a[1] = bfHi(sv.x); a[2] = bfLo(sv.y); a[3] = bfHi(sv.y);
    a[4] = bfLo(sv.z); a[5] = bfHi(sv.z); a[6] = bfLo(sv.w); a[7] = bfHi(sv.w);
  }

  for (int e = 0; __any(e < deg); e += 4) {
    int id[4];
    bool ok[4];
#pragma unroll
    for (int q = 0; q < 4; ++q) {
      int ei = e + q;
      ok[q] = ei < deg;
      id[q] = csr[s0 + max(min(ei, deg - 1), 0)];      // slot-uniform broadcast
    }
    uint4 v[4];
#pragma unroll
    for (int q = 0; q < 4; ++q)
      v[q] = hsq[(((unsigned)id[q]) << 3) + pos];      // 4 independent row loads
#pragma unroll
    for (int q = 0; q < 4; ++q) {
      if (ok[q]) {
        a[0] += bfLo(v[q].x); a[1] += bfHi(v[q].x);
        a[2] += bfLo(v[q].y); a[3] += bfHi(v[q].y);
        a[4] += bfLo(v[q].z); a[5] += bfHi(v[q].z);
        a[6] += bfLo(v[q].w); a[7] += bfHi(v[q].w);
      }
    }
  }

  float dv = dinv[node];
  float4 rA, rB;
  rA.x = fmaxf(fmaf(a[0], dv, bA.x), 0.f);
  rA.y = fmaxf(fmaf(a[1], dv, bA.y), 0.f);
  rA.z = fmaxf(fmaf(a[2], dv, bA.z), 0.f);
  rA.w = fmaxf(fmaf(a[3], dv, bA.w), 0.f);
  rB.x = fmaxf(fmaf(a[4], dv, bB.x), 0.f);
  rB.y = fmaxf(fmaf(a[5], dv, bB.y), 0.f);
  rB.z = fmaxf(fmaf(a[6], dv, bB.z), 0.f);
  rB.w = fmaxf(fmaf(a[7], dv, bB.w), 0.f);
  float4* op = reinterpret_cast<float4*>(out + (((size_t)node) << 6) + pos * 8);
  op[0] = rA;
  op[1] = rB;
}

// Stage-1 pool: wave handles 16 rows; batch sorted -> graph id wave-uniform;
// one fp32 atomicAdd per segment per channel.
__global__ __launch_bounds__(256) void k_pool1(const float* __restrict__ h,
                                               const int* __restrict__ batch,
                                               float* __restrict__ gsum, int N) {
  int c = threadIdx.x & 63;
  int w = threadIdx.x >> 6;
  int r0 = blockIdx.x * 64 + w * 16;
  if (r0 >= N) return;
  int r1 = min(r0 + 16, N);
  int gprev = batch[r0];
  float acc = 0.f;
  for (int r = r0; r < r1; ++r) {
    int g = batch[r];                        // wave-uniform
    if (g != gprev) { atomicAdd(&gsum[gprev * 64 + c], acc); acc = 0.f; gprev = g; }
    acc += h[(size_t)r * 64 + c];            // coalesced 256B row
  }
  atomicAdd(&gsum[gprev * 64 + c], acc);
}

// Final projection; per-block binary searches for segment sizes.
__global__ void k_final(const float* __restrict__ gsum, const int* __restrict__ batch,
                        const float* __restrict__ Wp, const float* __restrict__ bp,
                        float* __restrict__ out, int N) {
  __shared__ int lb[5];
  int t = threadIdx.x;
  int g0 = blockIdx.x * 4;
  if (t < 5) lb[t] = lowerb(batch, N, g0 + t);
  __syncthreads();
  int idx = blockIdx.x * 256 + t;
  int g = idx >> 6, o = idx & 63, gl = g & 3;
  float cinv = 1.0f / fmaxf((float)(lb[gl + 1] - lb[gl]), 1.0f);
  float acc = 0.f;
#pragma unroll
  for (int k = 0; k < 64; ++k) acc += gsum[g * 64 + k] * Wp[k * 64 + o];
  out[idx] = fmaf(acc, cinv, bp[o]);
}

extern "C" void kernel_launch(void* const* d_in, const int* in_sizes, int n_in,
                              void* d_out, int out_size, void* d_ws, size_t ws_size,
                              hipStream_t stream) {
  const float* x    = (const float*)d_in[0];
  const float* W1   = (const float*)d_in[1];
  const float* b1   = (const float*)d_in[2];
  const float* W2   = (const float*)d_in[3];
  const float* b2   = (const float*)d_in[4];
  const float* Wp   = (const float*)d_in[5];
  const float* bp   = (const float*)d_in[6];
  const int*   ei   = (const int*)d_in[7];
  const int*   batch= (const int*)d_in[8];
  float* out = (float*)d_out;

  const int N = N_NODES, E = N_EDGESC;
  const int* src  = ei;        // edge_index[0]
  const int* dstp = ei + E;    // edge_index[1]

  char* wsb = (char*)d_ws;
  size_t o = 0;
  auto alloc = [&](size_t bytes) -> void* {
    void* p = wsb + o;
    o = (o + bytes + 255) & ~(size_t)255;
    return p;
  };
  int*      bcnt   = (int*)alloc((size_t)NBUCK * NBLK * 4);
  int*      btot   = (int*)alloc(NBUCK * 4);
  unsigned* bbuf   = (unsigned*)alloc((size_t)E * 4);
  int*      row_off= (int*)alloc((size_t)(N + 1) * 4);
  int*      csr    = (int*)alloc((size_t)E * 4);
  float*    dinv   = (float*)alloc((size_t)N * 4);
  unsigned short* bufBF = (unsigned short*)alloc((size_t)N * 64 * 2);
  float*    bufF   = (float*)alloc((size_t)N * 64 * 4);
  float*    gsum   = (float*)alloc(64 * 64 * 4);

  int gN64 = (N + 63) / 64;           // 782
  int gG   = (N + 31) / 32;           // 1563 (4 waves x 8 nodes per block)

  k_hist<<<NBLK, 256, 0, stream>>>(dstp, bcnt, gsum, E);
  k_cscan<<<NBUCK, 256, 0, stream>>>(bcnt, btot);
  k_scatter<<<NBLK, 256, 0, stream>>>(src, dstp, bcnt, btot, bbuf, E);
  k_bsort<<<NBUCK, 512, 0, stream>>>(bbuf, btot, csr, row_off, dinv);

  k_gemm<128><<<gN64, 256, 0, stream>>>(x, W1, dinv, bufBF, N);
  k_gather<<<gG, 256, 0, stream>>>(bufBF, row_off, csr, dinv, b1, bufF, N);
  k_gemm<64><<<gN64, 256, 0, stream>>>(bufF, W2, dinv, bufBF, N);
  k_gather<<<gG, 256, 0, stream>>>(bufBF, row_off, csr, dinv, b2, bufF, N);

  k_pool1<<<gN64, 256, 0, stream>>>(bufF, batch, gsum, N);
  k_final<<<16, 256, 0, stream>>>(gsum, batch, Wp, bp, out, N);
}